// Round 14
// baseline (224.824 us; speedup 1.0000x reference)
//
#include <hip/hip_runtime.h>
#include <hip/hip_bf16.h>

typedef __attribute__((ext_vector_type(8))) short short8v;
typedef __attribute__((ext_vector_type(4))) float f32x4;

#define NW 200000
#define NT 20000
#define KIN 128
#define ODIM 256
#define NH 8
#define DH_ 32
#define FEAT_ 64
#define DEG_ 32
#define FFN_ 512
#define NTILE 3125

// Workspace layout (bytes)
#define WS_Z     0ull           // bf16 z fragment-order          102,400,000
#define WS_SSRC  102400000ull   // f32 s_src[Nw][8]                 6,400,000
#define WS_SDST  108800000ull   // f32 s_dst[Nt][8]                   640,000
#define WS_HBF   109440000ull   // bf16 h[Nt][256] (perm)          10,240,000
#define WS_TBF   119680000ull   // bf16 t[Nt][256]                 10,240,000
#define WS_B1T   129920000ull   // bf16 b1F fragments                  65,536
#define WS_PWT   129985536ull   // bf16 pwF fragments                 262,144
#define WS_W1T   130247680ull   // bf16 w1F fragments                 262,144
#define WS_W2T   130509824ull   // bf16 w2F fragments                 262,144
#define WS_R1F   130771968ull   // bf16 r1F fragments (B1@a)            4,096

// z fragment-order: ushort4 index = tile*4096 + (((g'*4+rl)*4+q)*4+lq)*16 + l16
// holds cols {g'*64+cf*16+l16 : cf=0..3} of row rl*16+lq*4+q (within tile).
// hbf position p holds orig col c(p) = (p>>6)*64 + (p&3)*16 + 2*((p>>3)&7) + ((p>>2)&1).

__device__ __forceinline__ unsigned short f2bf(float x) {
    __hip_bfloat16 b = __float2bfloat16(x);
    return *reinterpret_cast<unsigned short*>(&b);
}
__device__ __forceinline__ float bf2f(unsigned short u) {
    unsigned int v = ((unsigned int)u) << 16;
    return __uint_as_float(v);
}

// ---------------------------------------------------------------------------
// prep_w: fragment-ordered bf16 B-panels (1 KB fragments, lane l at l*16B).
// pwF bakes c(k) for k<256. r1F = fc_w contracted with attn_a[:, :32].
// ---------------------------------------------------------------------------
__global__ __launch_bounds__(256) void prep_w(const float* __restrict__ fc_w,
        const float* __restrict__ proj_w, const float* __restrict__ w1,
        const float* __restrict__ w2, const float* __restrict__ attn_a,
        unsigned short* __restrict__ b1f, unsigned short* __restrict__ pwf,
        unsigned short* __restrict__ w1f, unsigned short* __restrict__ w2f,
        unsigned short* __restrict__ r1f) {
    int i = blockIdx.x * 256 + threadIdx.x;   // 0..131071
    int j = i & 7, l = (i >> 3) & 63;
    int l16 = l & 15, lq = l >> 4;
    if (i < 32768) {                           // b1F: g<16, kk<4 (K=128, N=256)
        int kk = (i >> 9) & 3, g = i >> 11;
        int c = g * 16 + l16, k = kk * 32 + lq * 8 + j;
        int h = c >> 5, d = c & 31;
        b1f[i] = f2bf(fc_w[(h * KIN + k) * DH_ + d]);
    }
    if (i < 2048) {                            // r1F: kk<4, cols l16 (<8 valid)
        int kk = i >> 9, s = i & 511;
        int ll = s >> 3, jj = s & 7;
        int c16 = ll & 15, q16 = ll >> 4;
        int k = kk * 32 + q16 * 8 + jj;
        float v = 0.f;
        if (c16 < NH) {
            const float* fw = fc_w + (size_t)(c16 * KIN + k) * DH_;
            const float* aa = attn_a + c16 * 64;
            #pragma unroll
            for (int d = 0; d < DH_; ++d) v += fw[d] * aa[d];
        }
        r1f[i] = f2bf(v);
    }
    {   // pwF: g<16, kk<16 (K=512, N=256), B = proj_w with c(k) on k<256
        int kk = (i >> 9) & 15, g = i >> 13;
        int c = g * 16 + l16, k = kk * 32 + lq * 8 + j;
        int kp = k;
        if (k < 256)
            kp = ((k >> 6) << 6) + (k & 3) * 16 + 2 * ((k >> 3) & 7) + ((k >> 2) & 1);
        pwf[i] = f2bf(proj_w[(size_t)kp * ODIM + c]);
    }
    {   // w1F: g<32, kk<8 (K=256, N=512), B = ffn_w1
        int kk = (i >> 9) & 7, g = i >> 12;
        int c = g * 16 + l16, k = kk * 32 + lq * 8 + j;
        w1f[i] = f2bf(w1[(size_t)k * FFN_ + c]);
    }
    {   // w2F: g<16, kk<16 (K=512, N=256), B = ffn_w2
        int kk = (i >> 9) & 15, g = i >> 13;
        int c = g * 16 + l16, k = kk * 32 + lq * 8 + j;
        w2f[i] = f2bf(w2[(size_t)k * ODIM + c]);
    }
}

// prep_t: t -> bf16
__global__ __launch_bounds__(256) void prep_t(const float* __restrict__ t,
                                              unsigned short* __restrict__ tbf) {
    int i = blockIdx.x * 256 + threadIdx.x;   // 8 elems each
    const float4* p = (const float4*)(t + (size_t)i * 8);
    float4 a = p[0], b = p[1];
    short8v o;
    o[0] = (short)f2bf(a.x); o[1] = (short)f2bf(a.y);
    o[2] = (short)f2bf(a.z); o[3] = (short)f2bf(a.w);
    o[4] = (short)f2bf(b.x); o[5] = (short)f2bf(b.y);
    o[6] = (short)f2bf(b.z); o[7] = (short)f2bf(b.w);
    *((short8v*)tbf + i) = o;
}

// ---------------------------------------------------------------------------
// K1: z = w @ B1 (MFMA bf16). NO LDS, NO BARRIERS: each wave owns 16 rows x
// all 256 cols. A-fragments loaded direct global->reg (16x128B full lines,
// m89 fragment pattern), B-fragments from L2-hot b1f (1 KB each). s_src via
// MFMA with r1F straight from af. z stored from accumulators in fragment
// order (512B contiguous per (g',q) wave store). Pure streaming kernel.
// ---------------------------------------------------------------------------
__global__ __launch_bounds__(256) void k1_z(const float* __restrict__ w,
        const unsigned short* __restrict__ b1f, const unsigned short* __restrict__ r1f,
        unsigned short* __restrict__ z, float* __restrict__ s_src) {
    const int tid = threadIdx.x;
    const int wv = tid >> 6, l = tid & 63;
    const int l16 = l & 15, lq = l >> 4;
    const int rb = blockIdx.x * 4 + wv;        // row-block 0..12499
    const int tile = rb >> 2, rl = rb & 3;
    const int row0 = rb * 16;
    // A fragments: fp32 direct load -> bf16 (lane l: row l16, k = kk*32+lq*8+j)
    short8v af[4];
    #pragma unroll
    for (int kk = 0; kk < 4; ++kk) {
        const float* wp = w + (size_t)(row0 + l16) * KIN + kk * 32 + lq * 8;
        float4 v0 = *(const float4*)wp;
        float4 v1 = *(const float4*)(wp + 4);
        short8v a;
        a[0] = (short)f2bf(v0.x); a[1] = (short)f2bf(v0.y);
        a[2] = (short)f2bf(v0.z); a[3] = (short)f2bf(v0.w);
        a[4] = (short)f2bf(v1.x); a[5] = (short)f2bf(v1.y);
        a[6] = (short)f2bf(v1.z); a[7] = (short)f2bf(v1.w);
        af[kk] = a;
    }
    // s_src: rows row0..row0+15 (K=128 via r1F)
    {
        f32x4 sacc = (f32x4){0.f, 0.f, 0.f, 0.f};
        #pragma unroll
        for (int kk = 0; kk < 4; ++kk) {
            short8v rB = *(const short8v*)((const short*)r1f + ((kk << 9) + l * 8));
            sacc = __builtin_amdgcn_mfma_f32_16x16x32_bf16(af[kk], rB, sacc, 0, 0, 0);
        }
        if (l16 < NH) {
            #pragma unroll
            for (int q = 0; q < 4; ++q)
                s_src[(size_t)(row0 + lq * 4 + q) * NH + l16] = sacc[q];
        }
    }
    // main: 16 col-groups x 4 kk
    f32x4 acc[16];
    #pragma unroll
    for (int g = 0; g < 16; ++g) acc[g] = (f32x4){0.f, 0.f, 0.f, 0.f};
    #pragma unroll
    for (int g = 0; g < 16; ++g)
        #pragma unroll
        for (int kk = 0; kk < 4; ++kk) {
            short8v b = *(const short8v*)((const short*)b1f + (((g * 4 + kk) << 9) + l * 8));
            acc[g] = __builtin_amdgcn_mfma_f32_16x16x32_bf16(af[kk], b, acc[g], 0, 0, 0);
        }
    // z store: fragment order (identical addresses/bytes to the staged version)
    #pragma unroll
    for (int wq = 0; wq < 4; ++wq)
        #pragma unroll
        for (int q = 0; q < 4; ++q) {
            ushort4 u;
            u.x = f2bf(acc[wq * 4 + 0][q]); u.y = f2bf(acc[wq * 4 + 1][q]);
            u.z = f2bf(acc[wq * 4 + 2][q]); u.w = f2bf(acc[wq * 4 + 3][q]);
            ((ushort4*)z)[(size_t)tile * 4096 +
                          (size_t)((((wq * 4 + rl) * 4 + q) * 4 + lq) * 16 + l16)] = u;
        }
}

// ---------------------------------------------------------------------------
// K_sdst: s_dst[n,h] = topic_feat[n] . (dstfeat_w[h] @ attn_a[h,32:])
// ---------------------------------------------------------------------------
__global__ __launch_bounds__(256) void k_sdst(const float* __restrict__ topic_feat,
        const float* __restrict__ dstfeat_w, const float* __restrict__ attn_a,
        float* __restrict__ s_dst) {
    __shared__ float rS[NH * 65];
    __shared__ float tfS[32 * 65];
    const int tid = threadIdx.x;
    for (int i = tid; i < NH * FEAT_; i += 256) {
        int h = i >> 6, f = i & 63;
        const float* dw = dstfeat_w + (size_t)(h * FEAT_ + f) * DH_;
        const float* aa = attn_a + h * 64 + DH_;
        float s = 0.f;
        #pragma unroll
        for (int d = 0; d < DH_; ++d) s += dw[d] * aa[d];
        rS[h * 65 + f] = s;
    }
    const int n0 = blockIdx.x * 32;
    for (int i = tid; i < 32 * FEAT_; i += 256) {
        int n = i >> 6, f = i & 63;
        tfS[n * 65 + f] = topic_feat[(size_t)(n0 + n) * FEAT_ + f];
    }
    __syncthreads();
    int n = tid >> 3, h = tid & 7;
    float s = 0.f;
    #pragma unroll
    for (int f = 0; f < FEAT_; ++f) s += tfS[n * 65 + f] * rS[h * 65 + f];
    s_dst[(size_t)(n0 + n) * NH + h] = s;
}

// ---------------------------------------------------------------------------
// K2: per dst node softmax+aggregate. 1 wave/node, 4 nodes/block.
// Gathers fragment-ordered z; lane's 16B covers 8 permuted cols spanning the
// lane-group's two heads (pairs alternate); hbf written in permuted order.
// ---------------------------------------------------------------------------
__global__ __launch_bounds__(256) void k2_attn(const int* __restrict__ edge_src,
        const float* __restrict__ s_src, const float* __restrict__ s_dst,
        const unsigned short* __restrict__ z, unsigned short* __restrict__ hbf) {
    __shared__ int srcS[4][32];
    __shared__ float aS[4][32][8];
    const int tid = threadIdx.x;
    const int nd = tid >> 6, l = tid & 63;
    const int n = blockIdx.x * 4 + nd;
    if (l < 32) srcS[nd][l] = edge_src[(size_t)n * DEG_ + l];
    __syncthreads();
    {   // scores + per-head softmax (lane: e = l&31; heads h0..h0+3)
        int e = l & 31, h0 = (l >> 5) * 4;
        int s = srcS[nd][e];
        float4 ss = *(const float4*)(s_src + (size_t)s * NH + h0);
        float4 sd = *(const float4*)(s_dst + (size_t)n * NH + h0);
        float v[4] = {ss.x + sd.x, ss.y + sd.y, ss.z + sd.z, ss.w + sd.w};
        #pragma unroll
        for (int j = 0; j < 4; ++j) v[j] = (v[j] >= 0.f) ? v[j] : 0.01f * v[j];
        float al[4];
        #pragma unroll
        for (int j = 0; j < 4; ++j) {
            float m = v[j];
            #pragma unroll
            for (int off = 16; off >= 1; off >>= 1)
                m = fmaxf(m, __shfl_xor(m, off));
            float p = expf(v[j] - m);
            float su = p;
            #pragma unroll
            for (int off = 16; off >= 1; off >>= 1)
                su += __shfl_xor(su, off);
            al[j] = p / fmaxf(su, 1e-9f);
        }
        float4 a4 = {al[0], al[1], al[2], al[3]};
        *(float4*)(&aS[nd][e][h0]) = a4;
    }
    __syncthreads();
    {   // aggregation over fragment-ordered z
        const int half = l >> 5, cl = l & 31;
        const int wvh = cl >> 3, h0 = wvh * 2;
        const int lo8 = (cl & 7) * 8;
        float acc[8];
        #pragma unroll
        for (int j = 0; j < 8; ++j) acc[j] = 0.f;
        #pragma unroll 4
        for (int ee = 0; ee < 16; ++ee) {
            int e = ee * 2 + half;
            int sp = srcS[nd][e];
            float a_lo = aS[nd][e][h0], a_hi = aS[nd][e][h0 + 1];
            int rr = sp & 63;
            size_t off = (size_t)(sp >> 6) * 16384 +
                (size_t)(((((wvh * 4 + (rr >> 4)) * 4 + (rr & 3)) * 4 + ((rr >> 2) & 3)) * 64) + lo8);
            short8v zv = *(const short8v*)(z + off);
            #pragma unroll
            for (int u = 0; u < 8; ++u) {
                float a = ((u >> 1) & 1) ? a_hi : a_lo;
                acc[u] += a * bf2f((unsigned short)zv[u]);
            }
        }
        #pragma unroll
        for (int j = 0; j < 8; ++j)
            acc[j] += __shfl_xor(acc[j], 32);
        if (half == 0) {
            short8v o;
            #pragma unroll
            for (int j = 0; j < 8; ++j) {
                float v = (acc[j] > 0.f) ? acc[j] : expm1f(acc[j]);
                o[j] = (short)f2bf(v);
            }
            *(short8v*)(hbf + (size_t)n * ODIM + cl * 8) = o;
        }
    }
}

// ---------------------------------------------------------------------------
// K34: fused proj + LN + FFN + residual. M=32 rows/block, 4 waves.
// hp lives in GEMM0 accumulators; fragment-ordered B panels; pwF carries the
// h-column permutation so GEMM0 contracts correctly.
// ---------------------------------------------------------------------------
#define BUFP 524
#define XNP  268
__global__ __launch_bounds__(256, 3) void k34_ffn(const unsigned short* __restrict__ hbf,
        const unsigned short* __restrict__ tbf, const unsigned short* __restrict__ pwf,
        const float* __restrict__ proj_b, const float* __restrict__ ln_scale,
        const float* __restrict__ ln_bias, const unsigned short* __restrict__ w1f,
        const float* __restrict__ b1, const unsigned short* __restrict__ w2f,
        const float* __restrict__ b2, float* __restrict__ out) {
    __shared__ unsigned short buf[32 * BUFP];   // A0 [32][512] then inter [32][512]
    __shared__ unsigned short xnS[32 * XNP];    // xn bf16
    __shared__ float lnP[4][32], lnQ[4][32];
    __shared__ float muS[32], rsS[32];
    const int tid = threadIdx.x;
    const int row0 = blockIdx.x * 32;
    #pragma unroll
    for (int j = 0; j < 8; ++j) {
        int i = tid + j * 256;                  // 0..2047
        int r = i >> 6, cq = i & 63;
        ushort4 hv = *(const ushort4*)(hbf + (size_t)(row0 + r) * ODIM + cq * 4);
        *(ushort4*)(&buf[r * BUFP + cq * 4]) = hv;
        ushort4 tv = *(const ushort4*)(tbf + (size_t)(row0 + r) * ODIM + cq * 4);
        *(ushort4*)(&buf[r * BUFP + 256 + cq * 4]) = tv;
    }
    __syncthreads();
    const int wv = tid >> 6, l = tid & 63;
    const int l16 = l & 15, lq = l >> 4;
    const int l8 = l * 8;                        // short offset within fragment
    // ---------------- GEMM0: hp[32][256] = A0[32][512] @ proj_w + b ----------
    f32x4 acc0[2][4];
    #pragma unroll
    for (int rf = 0; rf < 2; ++rf)
        #pragma unroll
        for (int cf = 0; cf < 4; ++cf) acc0[rf][cf] = (f32x4){0.f, 0.f, 0.f, 0.f};
    {
        short8v bp[2][4];
        #pragma unroll
        for (int cf = 0; cf < 4; ++cf)
            bp[0][cf] = *(const short8v*)((const short*)pwf + ((((wv * 4 + cf) * 16) << 9) + l8));
        #pragma unroll
        for (int kk = 0; kk < 16; ++kk) {
            const int cur = kk & 1;
            if (kk < 15) {
                #pragma unroll
                for (int cf = 0; cf < 4; ++cf)
                    bp[cur ^ 1][cf] = *(const short8v*)((const short*)pwf +
                        ((((wv * 4 + cf) * 16 + kk + 1) << 9) + l8));
            }
            short8v a0 = *(const short8v*)(&buf[l16 * BUFP + kk * 32 + lq * 8]);
            short8v a1 = *(const short8v*)(&buf[(16 + l16) * BUFP + kk * 32 + lq * 8]);
            #pragma unroll
            for (int cf = 0; cf < 4; ++cf) {
                acc0[0][cf] = __builtin_amdgcn_mfma_f32_16x16x32_bf16(a0, bp[cur][cf], acc0[0][cf], 0, 0, 0);
                acc0[1][cf] = __builtin_amdgcn_mfma_f32_16x16x32_bf16(a1, bp[cur][cf], acc0[1][cf], 0, 0, 0);
            }
        }
    }
    #pragma unroll
    for (int cf = 0; cf < 4; ++cf) {
        float bb = proj_b[wv * 64 + cf * 16 + l16];
        #pragma unroll
        for (int rf = 0; rf < 2; ++rf)
            #pragma unroll
            for (int q = 0; q < 4; ++q) acc0[rf][cf][q] += bb;
    }
    // ---------------- LN stats (hp stays in registers) ----------------------
    #pragma unroll
    for (int rf = 0; rf < 2; ++rf)
        #pragma unroll
        for (int q = 0; q < 4; ++q) {
            float s = 0.f, s2 = 0.f;
            #pragma unroll
            for (int cf = 0; cf < 4; ++cf) {
                float v = acc0[rf][cf][q];
                s += v; s2 += v * v;
            }
            s  += __shfl_xor(s, 1);  s2 += __shfl_xor(s2, 1);
            s  += __shfl_xor(s, 2);  s2 += __shfl_xor(s2, 2);
            s  += __shfl_xor(s, 4);  s2 += __shfl_xor(s2, 4);
            s  += __shfl_xor(s, 8);  s2 += __shfl_xor(s2, 8);
            if (l16 == 0) {
                int row = rf * 16 + lq * 4 + q;
                lnP[wv][row] = s; lnQ[wv][row] = s2;
            }
        }
    __syncthreads();
    if (tid < 32) {
        float s = lnP[0][tid] + lnP[1][tid] + lnP[2][tid] + lnP[3][tid];
        float s2 = lnQ[0][tid] + lnQ[1][tid] + lnQ[2][tid] + lnQ[3][tid];
        float mu = s * (1.f / 256.f);
        float var = s2 * (1.f / 256.f) - mu * mu;
        muS[tid] = mu;
        rsS[tid] = rsqrtf(var + 1e-6f);
    }
    __syncthreads();
    // ---------------- xn = LN(hp)*scale + bias -> LDS bf16 -------------------
    #pragma unroll
    for (int cf = 0; cf < 4; ++cf) {
        int c = wv * 64 + cf * 16 + l16;
        float ls = ln_scale[c], lb = ln_bias[c];
        #pragma unroll
        for (int rf = 0; rf < 2; ++rf)
            #pragma unroll
            for (int q = 0; q < 4; ++q) {
                int row = rf * 16 + lq * 4 + q;
                float x = (acc0[rf][cf][q] - muS[row]) * rsS[row] * ls + lb;
                xnS[row * XNP + c] = f2bf(x);
            }
    }
    __syncthreads();
    // ---------------- GEMM1: C1[32][512] = xn[32][256] @ W1, gelu -> buf -----
    {
        f32x4 acc1[2][8];
        #pragma unroll
        for (int rf = 0; rf < 2; ++rf)
            #pragma unroll
            for (int cf = 0; cf < 8; ++cf) acc1[rf][cf] = (f32x4){0.f, 0.f, 0.f, 0.f};
        #pragma unroll 2
        for (int kk = 0; kk < 8; ++kk) {
            short8v a0 = *(const short8v*)(&xnS[l16 * XNP + kk * 32 + lq * 8]);
            short8v a1 = *(const short8v*)(&xnS[(16 + l16) * XNP + kk * 32 + lq * 8]);
            #pragma unroll
            for (int cf = 0; cf < 8; ++cf) {
                short8v b = *(const short8v*)((const short*)w1f +
                    ((((wv * 8 + cf) * 8 + kk) << 9) + l8));
                acc1[0][cf] = __builtin_amdgcn_mfma_f32_16x16x32_bf16(a0, b, acc1[0][cf], 0, 0, 0);
                acc1[1][cf] = __builtin_amdgcn_mfma_f32_16x16x32_bf16(a1, b, acc1[1][cf], 0, 0, 0);
            }
        }
        #pragma unroll
        for (int cf = 0; cf < 8; ++cf) {
            int c = wv * 128 + cf * 16 + l16;
            float bb = b1[c];
            #pragma unroll
            for (int rf = 0; rf < 2; ++rf)
                #pragma unroll
                for (int q = 0; q < 4; ++q) {
                    float x = acc1[rf][cf][q] + bb;
                    x = 0.5f * x * (1.f + erff(x * 0.70710678118654752f));
                    buf[(rf * 16 + lq * 4 + q) * BUFP + c] = f2bf(x);
                }
        }
    }
    __syncthreads();
    // ---------------- GEMM2: out = inter[32][512] @ W2 + b2 + hp -------------
    {
        f32x4 acc2[2][4];
        #pragma unroll
        for (int rf = 0; rf < 2; ++rf)
            #pragma unroll
            for (int cf = 0; cf < 4; ++cf) acc2[rf][cf] = (f32x4){0.f, 0.f, 0.f, 0.f};
        short8v bp[2][4];
        #pragma unroll
        for (int cf = 0; cf < 4; ++cf)
            bp[0][cf] = *(const short8v*)((const short*)w2f + ((((wv * 4 + cf) * 16) << 9) + l8));
        #pragma unroll
        for (int kk = 0; kk < 16; ++kk) {
            const int cur = kk & 1;
            if (kk < 15) {
                #pragma unroll
                for (int cf = 0; cf < 4; ++cf)
                    bp[cur ^ 1][cf] = *(const short8v*)((const short*)w2f +
                        ((((wv * 4 + cf) * 16 + kk + 1) << 9) + l8));
            }
            short8v a0 = *(const short8v*)(&buf[l16 * BUFP + kk * 32 + lq * 8]);
            short8v a1 = *(const short8v*)(&buf[(16 + l16) * BUFP + kk * 32 + lq * 8]);
            #pragma unroll
            for (int cf = 0; cf < 4; ++cf) {
                acc2[0][cf] = __builtin_amdgcn_mfma_f32_16x16x32_bf16(a0, bp[cur][cf], acc2[0][cf], 0, 0, 0);
                acc2[1][cf] = __builtin_amdgcn_mfma_f32_16x16x32_bf16(a1, bp[cur][cf], acc2[1][cf], 0, 0, 0);
            }
        }
        #pragma unroll
        for (int cf = 0; cf < 4; ++cf) {
            int c = wv * 64 + cf * 16 + l16;
            float bb = b2[c];
            #pragma unroll
            for (int rf = 0; rf < 2; ++rf)
                #pragma unroll
                for (int q = 0; q < 4; ++q) {
                    int row = rf * 16 + lq * 4 + q;
                    out[(size_t)(row0 + row) * ODIM + c] =
                        acc2[rf][cf][q] + bb + acc0[rf][cf][q];
                }
        }
    }
}

extern "C" void kernel_launch(void* const* d_in, const int* in_sizes, int n_in,
                              void* d_out, int out_size, void* d_ws, size_t ws_size,
                              hipStream_t stream) {
    const float* w          = (const float*)d_in[0];
    const float* t          = (const float*)d_in[1];
    const float* topic_feat = (const float*)d_in[2];
    const int*   edge_src   = (const int*)d_in[3];
    // d_in[4] = edge_dst: repeat(arange(Nt), DEG) -> implicit
    const float* fc_w       = (const float*)d_in[5];
    const float* attn_a     = (const float*)d_in[6];
    const float* dstfeat_w  = (const float*)d_in[7];
    const float* proj_w     = (const float*)d_in[8];
    const float* proj_b     = (const float*)d_in[9];
    const float* ffn_w1     = (const float*)d_in[10];
    const float* ffn_b1     = (const float*)d_in[11];
    const float* ffn_w2     = (const float*)d_in[12];
    const float* ffn_b2     = (const float*)d_in[13];
    const float* ln_scale   = (const float*)d_in[14];
    const float* ln_bias    = (const float*)d_in[15];
    float* out = (float*)d_out;

    char* ws = (char*)d_ws;
    unsigned short* z    = (unsigned short*)(ws + WS_Z);
    float* s_src         = (float*)(ws + WS_SSRC);
    float* s_dst         = (float*)(ws + WS_SDST);
    unsigned short* hbf  = (unsigned short*)(ws + WS_HBF);
    unsigned short* tbf  = (unsigned short*)(ws + WS_TBF);
    unsigned short* b1f  = (unsigned short*)(ws + WS_B1T);
    unsigned short* pwf  = (unsigned short*)(ws + WS_PWT);
    unsigned short* w1f  = (unsigned short*)(ws + WS_W1T);
    unsigned short* w2f  = (unsigned short*)(ws + WS_W2T);
    unsigned short* r1f  = (unsigned short*)(ws + WS_R1F);

    hipLaunchKernelGGL(prep_w, dim3(512),  dim3(256), 0, stream,
                       fc_w, proj_w, ffn_w1, ffn_w2, attn_a, b1f, pwf, w1f, w2f, r1f);
    hipLaunchKernelGGL(prep_t, dim3(2500), dim3(256), 0, stream, t, tbf);
    hipLaunchKernelGGL(k1_z,   dim3(NTILE), dim3(256), 0, stream,
                       w, b1f, r1f, z, s_src);
    hipLaunchKernelGGL(k_sdst, dim3(NT / 32), dim3(256), 0, stream,
                       topic_feat, dstfeat_w, attn_a, s_dst);
    hipLaunchKernelGGL(k2_attn, dim3(NT / 4), dim3(256), 0, stream,
                       edge_src, s_src, s_dst, z, hbf);
    hipLaunchKernelGGL(k34_ffn, dim3(NT / 32), dim3(256), 0, stream,
                       hbf, tbf, pwf, proj_b, ln_scale, ln_bias,
                       w1f, ffn_b1, w2f, ffn_b2, out);
}

// Round 15
// 171.199 us; speedup vs baseline: 1.3132x; 1.3132x over previous
//
#include <hip/hip_runtime.h>
#include <hip/hip_bf16.h>

typedef __attribute__((ext_vector_type(8))) short short8v;
typedef __attribute__((ext_vector_type(4))) float f32x4;

#define NW 200000
#define NT 20000
#define KIN 128
#define ODIM 256
#define NH 8
#define DH_ 32
#define FEAT_ 64
#define DEG_ 32
#define FFN_ 512

// Workspace layout (bytes)
#define WS_Z     0ull           // bf16 z[Nw][256] (in-row perm)  102,400,000
#define WS_SSRC  102400000ull   // f32 s_src[Nw][8]                 6,400,000
#define WS_SDST  108800000ull   // f32 s_dst[Nt][8]                   640,000
#define WS_TBF   119680000ull   // bf16 t[Nt][256]                 10,240,000
#define WS_B1T   129920000ull   // bf16 b1F fragments                  65,536
#define WS_PWT   129985536ull   // bf16 pwF fragments                 262,144
#define WS_W1T   130247680ull   // bf16 w1F fragments                 262,144
#define WS_W2T   130509824ull   // bf16 w2F fragments                 262,144
#define WS_ABT   130771968ull   // bf16 aBT[16][256] (perm k)           8,192

// In-row column permutation: position p holds original column
// c(p) = (p>>6)*64 + (p&3)*16 + ((p>>2)&15); head(p) = (p>>6)*2 + ((p>>1)&1).

__device__ __forceinline__ unsigned short f2bf(float x) {
    __hip_bfloat16 b = __float2bfloat16(x);
    return *reinterpret_cast<unsigned short*>(&b);
}
__device__ __forceinline__ float bf2f(unsigned short u) {
    unsigned int v = ((unsigned int)u) << 16;
    return __uint_as_float(v);
}

// ---------------------------------------------------------------------------
// prep_w: fragment-ordered bf16 B-panels (1 KB fragments, lane l at l*16B).
// pwF bakes c(k) for k<256; aBT generated in permuted k-order.
// ---------------------------------------------------------------------------
__global__ __launch_bounds__(256) void prep_w(const float* __restrict__ fc_w,
        const float* __restrict__ proj_w, const float* __restrict__ w1,
        const float* __restrict__ w2, const float* __restrict__ attn_a,
        unsigned short* __restrict__ b1f, unsigned short* __restrict__ pwf,
        unsigned short* __restrict__ w1f, unsigned short* __restrict__ w2f,
        unsigned short* __restrict__ abt) {
    int i = blockIdx.x * 256 + threadIdx.x;   // 0..131071
    int j = i & 7, l = (i >> 3) & 63;
    int l16 = l & 15, lq = l >> 4;
    if (i < 32768) {                           // b1F: g<16, kk<4 (K=128, N=256)
        int kk = (i >> 9) & 3, g = i >> 11;
        int c = g * 16 + l16, k = kk * 32 + lq * 8 + j;
        int h = c >> 5, d = c & 31;
        b1f[i] = f2bf(fc_w[(h * KIN + k) * DH_ + d]);
    }
    if (i < 4096) {                            // aBT[h][p] permuted k-order
        int h = i >> 8, p = i & 255;
        int c = (p >> 6) * 64 + (p & 3) * 16 + ((p >> 2) & 15);
        abt[i] = ((c >> 5) == h) ? f2bf(attn_a[h * 64 + (c & 31)]) : (unsigned short)0;
    }
    {   // pwF: g<16, kk<16 (K=512, N=256), B = proj_w with c(k) on k<256
        int kk = (i >> 9) & 15, g = i >> 13;
        int c = g * 16 + l16, k = kk * 32 + lq * 8 + j;
        int kp = k;
        if (k < 256)
            kp = ((k >> 6) << 6) + (k & 3) * 16 + ((k >> 2) & 15);
        pwf[i] = f2bf(proj_w[(size_t)kp * ODIM + c]);
    }
    {   // w1F: g<32, kk<8 (K=256, N=512), B = ffn_w1
        int kk = (i >> 9) & 7, g = i >> 12;
        int c = g * 16 + l16, k = kk * 32 + lq * 8 + j;
        w1f[i] = f2bf(w1[(size_t)k * FFN_ + c]);
    }
    {   // w2F: g<16, kk<16 (K=512, N=256), B = ffn_w2
        int kk = (i >> 9) & 15, g = i >> 13;
        int c = g * 16 + l16, k = kk * 32 + lq * 8 + j;
        w2f[i] = f2bf(w2[(size_t)k * ODIM + c]);
    }
}

// prep_t: t -> bf16
__global__ __launch_bounds__(256) void prep_t(const float* __restrict__ t,
                                              unsigned short* __restrict__ tbf) {
    int i = blockIdx.x * 256 + threadIdx.x;   // 8 elems each
    const float4* p = (const float4*)(t + (size_t)i * 8);
    float4 a = p[0], b = p[1];
    short8v o;
    o[0] = (short)f2bf(a.x); o[1] = (short)f2bf(a.y);
    o[2] = (short)f2bf(a.z); o[3] = (short)f2bf(a.w);
    o[4] = (short)f2bf(b.x); o[5] = (short)f2bf(b.y);
    o[6] = (short)f2bf(b.z); o[7] = (short)f2bf(b.w);
    *((short8v*)tbf + i) = o;
}

// ---------------------------------------------------------------------------
// K1: z = w @ B1 (MFMA bf16); s_src via MFMA with permuted aBT. (r11 verbatim)
// Persistent 5-tile pipeline, 2 barriers/tile. zR repack uses the in-row
// permutation -> ds_write_b64; 1 KB contiguous row stores.
// ---------------------------------------------------------------------------
#define ZRP 264
#define TPB 5
__global__ __launch_bounds__(256) void k1_z(const float* __restrict__ w,
        const unsigned short* __restrict__ b1f, const unsigned short* __restrict__ abt,
        unsigned short* __restrict__ z, float* __restrict__ s_src) {
    __shared__ unsigned short aS[2][64 * 136];  // 34816 B
    __shared__ unsigned short zR[64 * ZRP];     // 33792 B
    const int tid = threadIdx.x;
    const int wv = tid >> 6, l = tid & 63;
    const int l16 = l & 15, lq = l >> 4;
    const int tile0 = blockIdx.x * TPB;
    float4 vb[8];
    #pragma unroll
    for (int j = 0; j < 8; ++j) {
        int i = tid + j * 256;
        int r = i >> 5, kq = i & 31;
        vb[j] = *(const float4*)(w + (size_t)(tile0 * 64 + r) * KIN + kq * 4);
    }
    #pragma unroll
    for (int j = 0; j < 8; ++j) {
        int i = tid + j * 256;
        int r = i >> 5, kq = i & 31;
        ushort4 u;
        u.x = f2bf(vb[j].x); u.y = f2bf(vb[j].y);
        u.z = f2bf(vb[j].z); u.w = f2bf(vb[j].w);
        *(ushort4*)(&aS[0][r * 136 + kq * 4]) = u;
    }
    for (int t = 0; t < TPB; ++t) {
        const int cur = t & 1;
        const int row0 = (tile0 + t) * 64;
        if (t < TPB - 1) {
            #pragma unroll
            for (int j = 0; j < 8; ++j) {
                int i = tid + j * 256;
                int r = i >> 5, kq = i & 31;
                vb[j] = *(const float4*)(w + (size_t)(row0 + 64 + r) * KIN + kq * 4);
            }
        }
        __syncthreads();                        // B1: aS[cur] ready, zR readers done
        f32x4 acc[4][4];
        #pragma unroll
        for (int a = 0; a < 4; ++a)
            #pragma unroll
            for (int b = 0; b < 4; ++b)
                acc[a][b] = (f32x4){0.f, 0.f, 0.f, 0.f};
        #pragma unroll
        for (int kk = 0; kk < 4; ++kk) {
            short8v af[4], bfr[4];
            #pragma unroll
            for (int rf = 0; rf < 4; ++rf)
                af[rf] = *(const short8v*)(&aS[cur][(rf * 16 + l16) * 136 + kk * 32 + lq * 8]);
            #pragma unroll
            for (int cf = 0; cf < 4; ++cf)
                bfr[cf] = *(const short8v*)((const short*)b1f +
                            ((((wv * 4 + cf) * 4 + kk) << 9) + l * 8));
            #pragma unroll
            for (int rf = 0; rf < 4; ++rf)
                #pragma unroll
                for (int cf = 0; cf < 4; ++cf)
                    acc[rf][cf] = __builtin_amdgcn_mfma_f32_16x16x32_bf16(
                        af[rf], bfr[cf], acc[rf][cf], 0, 0, 0);
        }
        // repack: permuted in-row layout -> one ds_write_b64 per (rl,q)
        #pragma unroll
        for (int rl = 0; rl < 4; ++rl)
            #pragma unroll
            for (int q = 0; q < 4; ++q) {
                int row = rl * 16 + lq * 4 + q;
                ushort4 u;
                u.x = f2bf(acc[rl][0][q]); u.y = f2bf(acc[rl][1][q]);
                u.z = f2bf(acc[rl][2][q]); u.w = f2bf(acc[rl][3][q]);
                *(ushort4*)(&zR[row * ZRP + wv * 64 + l16 * 4]) = u;
            }
        __syncthreads();                        // B2: zR ready
        {   // s_src: wave wv owns rows 16wv..16wv+15 (K=256 via permuted aBT)
            const int base = wv * 16;
            f32x4 sacc = (f32x4){0.f, 0.f, 0.f, 0.f};
            #pragma unroll
            for (int kk = 0; kk < 8; ++kk) {
                short8v a = *(const short8v*)(&zR[(base + l16) * ZRP + kk * 32 + lq * 8]);
                short8v b = *(const short8v*)((const short*)abt + (size_t)l16 * 256 + kk * 32 + lq * 8);
                sacc = __builtin_amdgcn_mfma_f32_16x16x32_bf16(a, b, sacc, 0, 0, 0);
            }
            if (l16 < NH) {
                #pragma unroll
                for (int q = 0; q < 4; ++q)
                    s_src[(size_t)(row0 + base + lq * 4 + q) * NH + l16] = sacc[q];
            }
        }
        // coalesced z store: 8 x ushort8 per thread (64 rows, permuted cols)
        #pragma unroll
        for (int j = 0; j < 8; ++j) {
            int idx = tid + j * 256;             // 0..2047
            int r = idx >> 5, ch = idx & 31;
            short8v v = *(const short8v*)(&zR[r * ZRP + ch * 8]);
            *(short8v*)(z + (size_t)(row0 + r) * ODIM + ch * 8) = v;
        }
        if (t < TPB - 1) {
            #pragma unroll
            for (int j = 0; j < 8; ++j) {
                int i = tid + j * 256;
                int r = i >> 5, kq = i & 31;
                ushort4 u;
                u.x = f2bf(vb[j].x); u.y = f2bf(vb[j].y);
                u.z = f2bf(vb[j].z); u.w = f2bf(vb[j].w);
                *(ushort4*)(&aS[cur ^ 1][r * 136 + kq * 4]) = u;
            }
        }
    }
}

// ---------------------------------------------------------------------------
// K_sdst: s_dst[n,h] = topic_feat[n] . (dstfeat_w[h] @ attn_a[h,32:])
// ---------------------------------------------------------------------------
__global__ __launch_bounds__(256) void k_sdst(const float* __restrict__ topic_feat,
        const float* __restrict__ dstfeat_w, const float* __restrict__ attn_a,
        float* __restrict__ s_dst) {
    __shared__ float rS[NH * 65];
    __shared__ float tfS[32 * 65];
    const int tid = threadIdx.x;
    for (int i = tid; i < NH * FEAT_; i += 256) {
        int h = i >> 6, f = i & 63;
        const float* dw = dstfeat_w + (size_t)(h * FEAT_ + f) * DH_;
        const float* aa = attn_a + h * 64 + DH_;
        float s = 0.f;
        #pragma unroll
        for (int d = 0; d < DH_; ++d) s += dw[d] * aa[d];
        rS[h * 65 + f] = s;
    }
    const int n0 = blockIdx.x * 32;
    for (int i = tid; i < 32 * FEAT_; i += 256) {
        int n = i >> 6, f = i & 63;
        tfS[n * 65 + f] = topic_feat[(size_t)(n0 + n) * FEAT_ + f];
    }
    __syncthreads();
    int n = tid >> 3, h = tid & 7;
    float s = 0.f;
    #pragma unroll
    for (int f = 0; f < FEAT_; ++f) s += tfS[n * 65 + f] * rS[h * 65 + f];
    s_dst[(size_t)(n0 + n) * NH + h] = s;
}

// ---------------------------------------------------------------------------
// K234: FUSED attention + proj + LN + FFN + residual. 32 nodes/block, 4 waves.
// Phase 0: each wave gathers/softmaxes/aggregates its 8 nodes directly into
// the buf LDS rows (permuted cols) - no hbf round-trip. alpha parks in the
// xnS region (dead until LN). Phases 1-4: identical to the old k34.
// ---------------------------------------------------------------------------
#define BUFP 524
#define XNP  268
__global__ __launch_bounds__(256, 3) void k234(const int* __restrict__ edge_src,
        const float* __restrict__ s_src, const float* __restrict__ s_dst,
        const unsigned short* __restrict__ z, const unsigned short* __restrict__ tbf,
        const unsigned short* __restrict__ pwf, const float* __restrict__ proj_b,
        const float* __restrict__ ln_scale, const float* __restrict__ ln_bias,
        const unsigned short* __restrict__ w1f, const float* __restrict__ b1,
        const unsigned short* __restrict__ w2f, const float* __restrict__ b2,
        float* __restrict__ out) {
    __shared__ __align__(16) unsigned short buf[32 * BUFP];  // h(perm)+t, then inter
    __shared__ __align__(16) unsigned short xnS[32 * XNP];   // phase0: alpha[4][32][8]
    __shared__ float lnP[4][32], lnQ[4][32];
    __shared__ float muS[32], rsS[32];
    const int tid = threadIdx.x;
    const int row0 = blockIdx.x * 32;
    const int wv = tid >> 6, l = tid & 63;
    const int l16 = l & 15, lq = l >> 4;
    const int l8 = l * 8;
    // stage t-half of buf
    #pragma unroll
    for (int j = 0; j < 8; ++j) {
        int i = tid + j * 256;                  // 0..2047
        int r = i >> 6, cq = i & 63;
        ushort4 tv = *(const ushort4*)(tbf + (size_t)(row0 + r) * ODIM + cq * 4);
        *(ushort4*)(&buf[r * BUFP + 256 + cq * 4]) = tv;
    }
    // ---------------- phase 0: attention for this wave's 8 nodes -------------
    {
        float* alphaW = (float*)xnS + wv * 256;   // [32][8] floats per wave
        for (int nd = 0; nd < 8; ++nd) {
            const int r = wv * 8 + nd;
            const int n = row0 + r;
            int srcv = edge_src[(size_t)n * DEG_ + (l & 31)];
            {   // scores + per-head softmax (lane: e=l&31; heads h0..h0+3)
                int h0 = (l >> 5) * 4;
                float4 ss = *(const float4*)(s_src + (size_t)srcv * NH + h0);
                float4 sd = *(const float4*)(s_dst + (size_t)n * NH + h0);
                float v[4] = {ss.x + sd.x, ss.y + sd.y, ss.z + sd.z, ss.w + sd.w};
                #pragma unroll
                for (int j = 0; j < 4; ++j) v[j] = (v[j] >= 0.f) ? v[j] : 0.01f * v[j];
                float al[4];
                #pragma unroll
                for (int j = 0; j < 4; ++j) {
                    float m = v[j];
                    #pragma unroll
                    for (int off = 16; off >= 1; off >>= 1)
                        m = fmaxf(m, __shfl_xor(m, off));
                    float p = expf(v[j] - m);
                    float su = p;
                    #pragma unroll
                    for (int off = 16; off >= 1; off >>= 1)
                        su += __shfl_xor(su, off);
                    al[j] = p / fmaxf(su, 1e-9f);
                }
                float4 a4 = {al[0], al[1], al[2], al[3]};
                *(float4*)(&alphaW[(l & 31) * 8 + h0]) = a4;
            }
            asm volatile("s_waitcnt lgkmcnt(0)" ::: "memory");  // alpha visible in-wave
            {   // aggregation: half-waves over even/odd edges; permuted z rows
                const int half = l >> 5, cl = l & 31;
                const int h0a = (cl >> 3) * 2;
                float acc[8];
                #pragma unroll
                for (int j = 0; j < 8; ++j) acc[j] = 0.f;
                #pragma unroll 4
                for (int ee = 0; ee < 16; ++ee) {
                    int e = ee * 2 + half;
                    int sp = __shfl(srcv, e);
                    float a_lo = alphaW[e * 8 + h0a];
                    float a_hi = alphaW[e * 8 + h0a + 1];
                    short8v zv = *(const short8v*)(z + (size_t)sp * ODIM + cl * 8);
                    #pragma unroll
                    for (int u = 0; u < 8; ++u) {
                        float a = ((u >> 1) & 1) ? a_hi : a_lo;
                        acc[u] += a * bf2f((unsigned short)zv[u]);
                    }
                }
                #pragma unroll
                for (int j = 0; j < 8; ++j)
                    acc[j] += __shfl_xor(acc[j], 32);
                if (half == 0) {
                    ushort4 o0, o1;
                    float v0 = (acc[0] > 0.f) ? acc[0] : expm1f(acc[0]);
                    float v1 = (acc[1] > 0.f) ? acc[1] : expm1f(acc[1]);
                    float v2 = (acc[2] > 0.f) ? acc[2] : expm1f(acc[2]);
                    float v3 = (acc[3] > 0.f) ? acc[3] : expm1f(acc[3]);
                    float v4 = (acc[4] > 0.f) ? acc[4] : expm1f(acc[4]);
                    float v5 = (acc[5] > 0.f) ? acc[5] : expm1f(acc[5]);
                    float v6 = (acc[6] > 0.f) ? acc[6] : expm1f(acc[6]);
                    float v7 = (acc[7] > 0.f) ? acc[7] : expm1f(acc[7]);
                    o0.x = f2bf(v0); o0.y = f2bf(v1); o0.z = f2bf(v2); o0.w = f2bf(v3);
                    o1.x = f2bf(v4); o1.y = f2bf(v5); o1.z = f2bf(v6); o1.w = f2bf(v7);
                    *(ushort4*)(&buf[r * BUFP + cl * 8]) = o0;
                    *(ushort4*)(&buf[r * BUFP + cl * 8 + 4]) = o1;
                }
            }
        }
    }
    __syncthreads();
    // ---------------- GEMM0: hp[32][256] = A0[32][512] @ proj_w + b ----------
    f32x4 acc0[2][4];
    #pragma unroll
    for (int rf = 0; rf < 2; ++rf)
        #pragma unroll
        for (int cf = 0; cf < 4; ++cf) acc0[rf][cf] = (f32x4){0.f, 0.f, 0.f, 0.f};
    {
        short8v bp[2][4];
        #pragma unroll
        for (int cf = 0; cf < 4; ++cf)
            bp[0][cf] = *(const short8v*)((const short*)pwf + ((((wv * 4 + cf) * 16) << 9) + l8));
        #pragma unroll
        for (int kk = 0; kk < 16; ++kk) {
            const int cur = kk & 1;
            if (kk < 15) {
                #pragma unroll
                for (int cf = 0; cf < 4; ++cf)
                    bp[cur ^ 1][cf] = *(const short8v*)((const short*)pwf +
                        ((((wv * 4 + cf) * 16 + kk + 1) << 9) + l8));
            }
            short8v a0 = *(const short8v*)(&buf[l16 * BUFP + kk * 32 + lq * 8]);
            short8v a1 = *(const short8v*)(&buf[(16 + l16) * BUFP + kk * 32 + lq * 8]);
            #pragma unroll
            for (int cf = 0; cf < 4; ++cf) {
                acc0[0][cf] = __builtin_amdgcn_mfma_f32_16x16x32_bf16(a0, bp[cur][cf], acc0[0][cf], 0, 0, 0);
                acc0[1][cf] = __builtin_amdgcn_mfma_f32_16x16x32_bf16(a1, bp[cur][cf], acc0[1][cf], 0, 0, 0);
            }
        }
    }
    #pragma unroll
    for (int cf = 0; cf < 4; ++cf) {
        float bb = proj_b[wv * 64 + cf * 16 + l16];
        #pragma unroll
        for (int rf = 0; rf < 2; ++rf)
            #pragma unroll
            for (int q = 0; q < 4; ++q) acc0[rf][cf][q] += bb;
    }
    // ---------------- LN stats (hp stays in registers) ----------------------
    #pragma unroll
    for (int rf = 0; rf < 2; ++rf)
        #pragma unroll
        for (int q = 0; q < 4; ++q) {
            float s = 0.f, s2 = 0.f;
            #pragma unroll
            for (int cf = 0; cf < 4; ++cf) {
                float v = acc0[rf][cf][q];
                s += v; s2 += v * v;
            }
            s  += __shfl_xor(s, 1);  s2 += __shfl_xor(s2, 1);
            s  += __shfl_xor(s, 2);  s2 += __shfl_xor(s2, 2);
            s  += __shfl_xor(s, 4);  s2 += __shfl_xor(s2, 4);
            s  += __shfl_xor(s, 8);  s2 += __shfl_xor(s2, 8);
            if (l16 == 0) {
                int row = rf * 16 + lq * 4 + q;
                lnP[wv][row] = s; lnQ[wv][row] = s2;
            }
        }
    __syncthreads();
    if (tid < 32) {
        float s = lnP[0][tid] + lnP[1][tid] + lnP[2][tid] + lnP[3][tid];
        float s2 = lnQ[0][tid] + lnQ[1][tid] + lnQ[2][tid] + lnQ[3][tid];
        float mu = s * (1.f / 256.f);
        float var = s2 * (1.f / 256.f) - mu * mu;
        muS[tid] = mu;
        rsS[tid] = rsqrtf(var + 1e-6f);
    }
    __syncthreads();
    // ---------------- xn = LN(hp)*scale + bias -> LDS bf16 (alpha now dead) --
    #pragma unroll
    for (int cf = 0; cf < 4; ++cf) {
        int c = wv * 64 + cf * 16 + l16;
        float ls = ln_scale[c], lb = ln_bias[c];
        #pragma unroll
        for (int rf = 0; rf < 2; ++rf)
            #pragma unroll
            for (int q = 0; q < 4; ++q) {
                int row = rf * 16 + lq * 4 + q;
                float x = (acc0[rf][cf][q] - muS[row]) * rsS[row] * ls + lb;
                xnS[row * XNP + c] = f2bf(x);
            }
    }
    __syncthreads();
    // ---------------- GEMM1: C1[32][512] = xn[32][256] @ W1, gelu -> buf -----
    {
        f32x4 acc1[2][8];
        #pragma unroll
        for (int rf = 0; rf < 2; ++rf)
            #pragma unroll
            for (int cf = 0; cf < 8; ++cf) acc1[rf][cf] = (f32x4){0.f, 0.f, 0.f, 0.f};
        #pragma unroll 2
        for (int kk = 0; kk < 8; ++kk) {
            short8v a0 = *(const short8v*)(&xnS[l16 * XNP + kk * 32 + lq * 8]);
            short8v a1 = *(const short8v*)(&xnS[(16 + l16) * XNP + kk * 32 + lq * 8]);
            #pragma unroll
            for (int cf = 0; cf < 8; ++cf) {
                short8v b = *(const short8v*)((const short*)w1f +
                    ((((wv * 8 + cf) * 8 + kk) << 9) + l8));
                acc1[0][cf] = __builtin_amdgcn_mfma_f32_16x16x32_bf16(a0, b, acc1[0][cf], 0, 0, 0);
                acc1[1][cf] = __builtin_amdgcn_mfma_f32_16x16x32_bf16(a1, b, acc1[1][cf], 0, 0, 0);
            }
        }
        #pragma unroll
        for (int cf = 0; cf < 8; ++cf) {
            int c = wv * 128 + cf * 16 + l16;
            float bb = b1[c];
            #pragma unroll
            for (int rf = 0; rf < 2; ++rf)
                #pragma unroll
                for (int q = 0; q < 4; ++q) {
                    float x = acc1[rf][cf][q] + bb;
                    x = 0.5f * x * (1.f + erff(x * 0.70710678118654752f));
                    buf[(rf * 16 + lq * 4 + q) * BUFP + c] = f2bf(x);
                }
        }
    }
    __syncthreads();
    // ---------------- GEMM2: out = inter[32][512] @ W2 + b2 + hp -------------
    {
        f32x4 acc2[2][4];
        #pragma unroll
        for (int rf = 0; rf < 2; ++rf)
            #pragma unroll
            for (int cf = 0; cf < 4; ++cf) acc2[rf][cf] = (f32x4){0.f, 0.f, 0.f, 0.f};
        short8v bp[2][4];
        #pragma unroll
        for (int cf = 0; cf < 4; ++cf)
            bp[0][cf] = *(const short8v*)((const short*)w2f + ((((wv * 4 + cf) * 16) << 9) + l8));
        #pragma unroll
        for (int kk = 0; kk < 16; ++kk) {
            const int cur = kk & 1;
            if (kk < 15) {
                #pragma unroll
                for (int cf = 0; cf < 4; ++cf)
                    bp[cur ^ 1][cf] = *(const short8v*)((const short*)w2f +
                        ((((wv * 4 + cf) * 16 + kk + 1) << 9) + l8));
            }
            short8v a0 = *(const short8v*)(&buf[l16 * BUFP + kk * 32 + lq * 8]);
            short8v a1 = *(const short8v*)(&buf[(16 + l16) * BUFP + kk * 32 + lq * 8]);
            #pragma unroll
            for (int cf = 0; cf < 4; ++cf) {
                acc2[0][cf] = __builtin_amdgcn_mfma_f32_16x16x32_bf16(a0, bp[cur][cf], acc2[0][cf], 0, 0, 0);
                acc2[1][cf] = __builtin_amdgcn_mfma_f32_16x16x32_bf16(a1, bp[cur][cf], acc2[1][cf], 0, 0, 0);
            }
        }
        #pragma unroll
        for (int cf = 0; cf < 4; ++cf) {
            int c = wv * 64 + cf * 16 + l16;
            float bb = b2[c];
            #pragma unroll
            for (int rf = 0; rf < 2; ++rf)
                #pragma unroll
                for (int q = 0; q < 4; ++q) {
                    int row = rf * 16 + lq * 4 + q;
                    out[(size_t)(row0 + row) * ODIM + c] =
                        acc2[rf][cf][q] + bb + acc0[rf][cf][q];
                }
        }
    }
}

extern "C" void kernel_launch(void* const* d_in, const int* in_sizes, int n_in,
                              void* d_out, int out_size, void* d_ws, size_t ws_size,
                              hipStream_t stream) {
    const float* w          = (const float*)d_in[0];
    const float* t          = (const float*)d_in[1];
    const float* topic_feat = (const float*)d_in[2];
    const int*   edge_src   = (const int*)d_in[3];
    // d_in[4] = edge_dst: repeat(arange(Nt), DEG) -> implicit
    const float* fc_w       = (const float*)d_in[5];
    const float* attn_a     = (const float*)d_in[6];
    const float* dstfeat_w  = (const float*)d_in[7];
    const float* proj_w     = (const float*)d_in[8];
    const float* proj_b     = (const float*)d_in[9];
    const float* ffn_w1     = (const float*)d_in[10];
    const float* ffn_b1     = (const float*)d_in[11];
    const float* ffn_w2     = (const float*)d_in[12];
    const float* ffn_b2     = (const float*)d_in[13];
    const float* ln_scale   = (const float*)d_in[14];
    const float* ln_bias    = (const float*)d_in[15];
    float* out = (float*)d_out;

    char* ws = (char*)d_ws;
    unsigned short* z    = (unsigned short*)(ws + WS_Z);
    float* s_src         = (float*)(ws + WS_SSRC);
    float* s_dst         = (float*)(ws + WS_SDST);
    unsigned short* tbf  = (unsigned short*)(ws + WS_TBF);
    unsigned short* b1f  = (unsigned short*)(ws + WS_B1T);
    unsigned short* pwf  = (unsigned short*)(ws + WS_PWT);
    unsigned short* w1f  = (unsigned short*)(ws + WS_W1T);
    unsigned short* w2f  = (unsigned short*)(ws + WS_W2T);
    unsigned short* abt  = (unsigned short*)(ws + WS_ABT);

    hipLaunchKernelGGL(prep_w, dim3(512),           dim3(256), 0, stream,
                       fc_w, proj_w, ffn_w1, ffn_w2, attn_a, b1f, pwf, w1f, w2f, abt);
    hipLaunchKernelGGL(prep_t, dim3(2500),          dim3(256), 0, stream, t, tbf);
    hipLaunchKernelGGL(k1_z,   dim3(NW / (64*TPB)), dim3(256), 0, stream,
                       w, b1f, abt, z, s_src);
    hipLaunchKernelGGL(k_sdst, dim3(NT / 32),       dim3(256), 0, stream,
                       topic_feat, dstfeat_w, attn_a, s_dst);
    hipLaunchKernelGGL(k234,   dim3(NT / 32),       dim3(256), 0, stream,
                       edge_src, s_src, s_dst, z, tbf, pwf, proj_b,
                       ln_scale, ln_bias, w1f, ffn_b1, w2f, ffn_b2, out);
}